// Round 4
// baseline (113.460 us; speedup 1.0000x reference)
//
#include <hip/hip_runtime.h>
#include <math.h>

// QuanvolutionPlus round 8: round-7 resubmission (round-7 bench was an infra
// failure: container died at acquire/push, kernel never ran). One defensive
// tweak: the staged-image LDS flush moved BEFORE the bfrag conversion so
// stg[7] (28 VGPR) dies before bfrag[7] (28 VGPR) materializes - lower peak
// pressure under the bounds(256,4) 128-VGPR cap. Otherwise byte-identical.
//
// Design recap (see round-7 header): rounds 4/6 both ~27us kernel with
// different matvec phases -> shared feature phase is the cost, stall-bound
// (~7us of issue vs 27us measured). Cause: 37 scattered global gathers/wave
// over a 100-150KB per-CU working set vs 32KB L1 -> L2 latency per patch.
//  - stage block's 8 images (25088B) into LDS once, coalesced float4.
//  - patch gathers from LDS (3x b64 + 3x b32), clamp+mask halo (verified).
//  - cls/q features in registers; after barrier they flush to f16 buffers
//    ALIASING the dead image buffer -> LDS 25856B, 6 blocks/CU.
//  - MFMA matvec (16x16x32 f16, K=800, 7/7/7/4 split), LDS partial sum,
//    16-lane shfl softmax: verbatim from round 6 (pass-verified).
//
// Index facts (verified rounds 1-6): cls flat n = c*196+p ; q flat n = 4p+k ;
// logits[o] = sum_n fused[n]*lin_w[o*784+n] + lin_b[o]. MFMA 16x16x32 f16:
// A row=lane&15, k=(lane>>4)*8+j ; B col=lane&15, same k ; D col=lane&15,
// row=(lane>>4)*4+reg.

typedef __fp16 h2 __attribute__((ext_vector_type(2)));
typedef __fp16 h4 __attribute__((ext_vector_type(4)));
typedef __fp16 h8 __attribute__((ext_vector_type(8)));
typedef float f32x4 __attribute__((ext_vector_type(4)));

#define NSAMP 8
#define FSTRIDE 808   // f16 elems/row: 784 data + 16 zeroed pad (k=784..799) + 8 slack

__device__ __forceinline__ float rfl(float v) {
    return __int_as_float(__builtin_amdgcn_readfirstlane(__float_as_int(v)));
}

__global__ __launch_bounds__(256, 4)
void quanv_fused(const float* __restrict__ x,
                 const float* __restrict__ conv_w,
                 const float* __restrict__ bn_gamma,
                 const float* __restrict__ bn_beta,
                 const float* __restrict__ bn_mean,
                 const float* __restrict__ bn_var,
                 const float* __restrict__ var_params,
                 const float* __restrict__ lin_w,
                 const float* __restrict__ lin_b,
                 float* __restrict__ out, int B)
{
    // 25856 B. Phase 1: float img[8][784] (25088 B). Phase 2 (after barrier):
    // __fp16 clsB[8][808] at +0, __fp16 qB[8][808] at +12928. pw aliases clsB.
    __shared__ __align__(16) unsigned char lds_raw[2 * NSAMP * FSTRIDE * 2];
    __fp16* clsB = (__fp16*)lds_raw;
    __fp16* qB   = (__fp16*)(lds_raw + NSAMP * FSTRIDE * 2);

    const int tid  = threadIdx.x;
    const int lane = tid & 63;
    const int wave = tid >> 6;

    // ---- A) image staging: 7 coalesced float4 loads/thread -> LDS ----
    {
        const int base4 = blockIdx.x * (NSAMP * 196);  // block's first float4 of x
        const int maxg4 = B * 196 - 1;
        float4 stg[7];
        #pragma unroll
        for (int t = 0; t < 7; ++t) {
            int g = base4 + tid + 256 * t;
            g = (g < maxg4) ? g : maxg4;              // tail-block clamp (dup reads ok)
            stg[t] = ((const float4*)x)[g];
        }
        #pragma unroll
        for (int t = 0; t < 7; ++t) {
            int idx = tid + 256 * t;
            if (idx < NSAMP * 196) ((float4*)lds_raw)[idx] = stg[t];
        }
    }

    // ---- B fragments (lin_w -> f16) to registers, 7 K-steps/wave ----
    const int bcol = lane & 15, bkg = lane >> 4;
    const __fp16 hz = (__fp16)0.f;
    const h8 hz8 = {hz, hz, hz, hz, hz, hz, hz, hz};
    h8 bfrag[7];
    #pragma unroll
    for (int t = 0; t < 7; ++t) {
        int st = wave * 7 + t;
        int kb = st * 32 + bkg * 8;
        h8 bf = hz8;
        if (bcol < 10 && kb < 784) {
            const float4* lw4 = (const float4*)(lin_w + bcol * 784 + kb);
            float4 v0 = lw4[0], v1 = lw4[1];
            h2 p0 = __builtin_amdgcn_cvt_pkrtz(v0.x, v0.y);
            h2 p1 = __builtin_amdgcn_cvt_pkrtz(v0.z, v0.w);
            h2 p2 = __builtin_amdgcn_cvt_pkrtz(v1.x, v1.y);
            h2 p3 = __builtin_amdgcn_cvt_pkrtz(v1.z, v1.w);
            h8 tv = {p0.x, p0.y, p1.x, p1.y, p2.x, p2.y, p3.x, p3.y};
            bf = tv;
        }
        bfrag[t] = bf;
    }

    // ---- uniform small params (SGPR via readfirstlane) ----
    float inv[4], addc[4];
    #pragma unroll
    for (int c = 0; c < 4; ++c) {
        float iv = bn_gamma[c] * rsqrtf(bn_var[c] + 1e-5f);
        inv[c]  = rfl(iv);
        addc[c] = rfl(bn_beta[c] - bn_mean[c] * iv);
    }
    float cv[4], sv[4];
    #pragma unroll
    for (int k = 0; k < 4; ++k) {
        float s, c;
        __sincosf(var_params[k] * 0.5f, &s, &c);
        sv[k] = rfl(s); cv[k] = rfl(c);
    }

    __syncthreads();   // (1) image visible

    // ---- feature phase: 32 lanes/sample, patches from LDS, results to regs ----
    const int s_loc = tid >> 5;    // sample in block (0..7)
    const int q32   = tid & 31;    // patch lane
    const float* imgS = (const float*)lds_raw + s_loc * 784;

    h4 clsr[7], qr[7];
    #pragma unroll
    for (int it = 0; it < 7; ++it) {
        int p  = q32 + 32 * it;
        int pc = (p < 196) ? p : 195;     // branchless; dead lanes compute p=195
        unsigned ii = (unsigned)pc / 14u;
        int j  = pc - (int)ii * 14;
        int rm = (int)ii * 56 + 2 * j;    // float index of x[2i][2j] in sample

        // 3x b64 + 3x b32 LDS reads; clamps keep indices in [0,783]
        float2 Rm = *(const float2*)(imgS + rm);              // a11 a12
        float2 Rb = *(const float2*)(imgS + rm + 28);         // a21 a22
        int rt = rm - 28; rt = (rt > 0) ? rt : 0;
        float2 Rt = *(const float2*)(imgS + rt);              // a01 a02 (row 2i-1)
        int cl = rm - 1;  cl = (cl > 0) ? cl : 0;
        float a10 = imgS[cl];                                 // x[2i][2j-1]
        float a20 = imgS[cl + 28];                            // x[2i+1][2j-1]
        int ct = cl - 28; ct = (ct > 0) ? ct : 0;
        float a00 = imgS[ct];                                 // x[2i-1][2j-1]

        float mt = (ii > 0u) ? 1.f : 0.f;
        float ml = (j  > 0 ) ? 1.f : 0.f;
        a00 *= mt * ml;
        float a01 = Rt.x * mt, a02 = Rt.y * mt;
        a10 *= ml;
        float a11 = Rm.x, a12 = Rm.y;
        a20 *= ml;
        float a21 = Rb.x, a22 = Rb.y;

        // conv (s_loaded weights) + BN + ReLU -> clsr
        float hc[4];
        #pragma unroll
        for (int c = 0; c < 4; ++c) {
            float h = conv_w[c*9+0]*a00 + conv_w[c*9+1]*a01 + conv_w[c*9+2]*a02
                    + conv_w[c*9+3]*a10 + conv_w[c*9+4]*a11 + conv_w[c*9+5]*a12
                    + conv_w[c*9+6]*a20 + conv_w[c*9+7]*a21 + conv_w[c*9+8]*a22;
            hc[c] = fmaxf(h * inv[c] + addc[c], 0.f);
        }
        h2 ca = __builtin_amdgcn_cvt_pkrtz(hc[0], hc[1]);
        h2 cb = __builtin_amdgcn_cvt_pkrtz(hc[2], hc[3]);
        h4 cq = {ca.x, ca.y, cb.x, cb.y};
        clsr[it] = cq;

        // quantum state evolution (round-4/6 verified chain)
        float ha = 0.5f * (a11 + a21);
        float hb = 0.5f * (a12 + a22);
        float c0, s0, c1, s1;
        __sincosf(ha, &s0, &c0);
        __sincosf(hb, &s1, &c1);
        float m00 = c0*c1, m01 = c0*s1;
        float m10 = s0*s1, m11 = s0*c1;                                  // enc + CNOT(0->1)
        float t00 = cv[0]*m00 - sv[0]*m10, t01 = cv[0]*m01 - sv[0]*m11;
        float t10 = sv[0]*m00 + cv[0]*m10, t11 = sv[0]*m01 + cv[0]*m11;  // RY(v0) w0
        float u00 = cv[1]*t00 - sv[1]*t01, u01 = sv[1]*t00 + cv[1]*t01;
        float u10 = cv[1]*t10 - sv[1]*t11, u11 = sv[1]*t10 + cv[1]*t11;  // RY(v1) w1
        float tmp = u01; u01 = u11; u11 = tmp;                            // CNOT(1->0)
        float p00 = cv[2]*u00 - sv[2]*u10, p01 = cv[2]*u01 - sv[2]*u11;
        float p10 = sv[2]*u00 + cv[2]*u10, p11 = sv[2]*u01 + cv[2]*u11;  // RY(v2) w0
        float q00 = cv[3]*p00 - sv[3]*p01, q01 = sv[3]*p00 + cv[3]*p01;
        float q10 = cv[3]*p10 - sv[3]*p11, q11 = sv[3]*p10 + cv[3]*p11;  // RY(v3) w1

        float z0 = q00*q00 + q01*q01 - q10*q10 - q11*q11;
        float z1 = q00*q00 + q10*q10 - q01*q01 - q11*q11;
        float x0 = 2.f * (q00*q10 + q01*q11);
        float x1 = 2.f * (q00*q01 + q10*q11);
        h2 zz = __builtin_amdgcn_cvt_pkrtz(z0, z1);
        h2 xx = __builtin_amdgcn_cvt_pkrtz(x0, x1);
        h4 qv = {zz.x, zz.y, xx.x, xx.y};
        qr[it] = qv;
    }

    __syncthreads();   // (2) all img reads done -> cls/q buffers may alias img

    // ---- flush: pad zeros + register features -> LDS f16 buffers ----
    if (tid < 128) {   // k=784..799 pad of both buffers (A must be clean)
        int r = tid >> 4, buf = (tid >> 3) & 1, w = tid & 7;
        int* wp = (int*)((buf ? qB : clsB) + r * FSTRIDE + 784);
        wp[w] = 0;
    }
    #pragma unroll
    for (int it = 0; it < 7; ++it) {
        int p = q32 + 32 * it;
        if (p < 196) {
            __fp16* cr = clsB + s_loc * FSTRIDE + p;   // n = c*196+p, imm offsets
            cr[0]   = clsr[it].x;
            cr[196] = clsr[it].y;
            cr[392] = clsr[it].z;
            cr[588] = clsr[it].w;
            *(h4*)(qB + s_loc * FSTRIDE + 4 * p) = qr[it];   // n = 4p+k
        }
    }

    __syncthreads();   // (3) features visible to all waves

    // ---- MFMA matvec: wave w owns K-steps 7w..7w+6 (st<25 valid) ----
    f32x4 acc = {0.f, 0.f, 0.f, 0.f};
    {
        const int arow = lane & 15, akg = lane >> 4;
        #pragma unroll
        for (int t = 0; t < 7; ++t) {
            int st = wave * 7 + t;
            if (st < 25) {   // wave-uniform branch
                h8 a = hz8;
                if (arow < NSAMP) {   // rows 8-15 feed zeros (MFMA half-waste: free)
                    int off = arow * FSTRIDE + st * 32 + akg * 8;
                    a = *(const h8*)(clsB + off) + *(const h8*)(qB + off); // fused add
                }
                acc = __builtin_amdgcn_mfma_f32_16x16x32_f16(a, bfrag[t], acc, 0, 0, 0);
            }
        }
    }

    __syncthreads();   // (4) all cls reads done -> safe to alias partials onto clsB
    float* pw = (float*)clsB;   // [4 waves][8 samples][16 classes]
    if (lane < 32) {            // D rows 0..7 live in lanes 0..31
        const int col = lane & 15, rb = (lane >> 4) * 4;
        #pragma unroll
        for (int r = 0; r < 4; ++r)
            pw[(wave * 8 + rb + r) * 16 + col] = acc[r];
    }
    __syncthreads();   // (5) partials visible

    // ---- cross-wave sum + per-sample softmax (16 lanes per sample) ----
    if (tid < 128) {
        const int c  = tid & 15;   // class
        const int sl = tid >> 4;   // sample in block (0..7)
        float L = pw[sl * 16 + c] + pw[(8 + sl) * 16 + c]
                + pw[(16 + sl) * 16 + c] + pw[(24 + sl) * 16 + c];
        L = (c < 10) ? (L + lin_b[c]) : -1e30f;
        float mx = L;
        mx = fmaxf(mx, __shfl_xor(mx, 1, 16));
        mx = fmaxf(mx, __shfl_xor(mx, 2, 16));
        mx = fmaxf(mx, __shfl_xor(mx, 4, 16));
        mx = fmaxf(mx, __shfl_xor(mx, 8, 16));
        float se = (c < 10) ? __expf(L - mx) : 0.f;
        se += __shfl_xor(se, 1, 16);
        se += __shfl_xor(se, 2, 16);
        se += __shfl_xor(se, 4, 16);
        se += __shfl_xor(se, 8, 16);
        const int sg2 = blockIdx.x * NSAMP + sl;
        if (c < 10 && sg2 < B)
            out[(size_t)sg2 * 10 + c] = L - mx - __logf(se);
    }
}

extern "C" void kernel_launch(void* const* d_in, const int* in_sizes, int n_in,
                              void* d_out, int out_size, void* d_ws, size_t ws_size,
                              hipStream_t stream) {
    const float* x          = (const float*)d_in[0];
    const float* conv_w     = (const float*)d_in[1];
    const float* bn_gamma   = (const float*)d_in[2];
    const float* bn_beta    = (const float*)d_in[3];
    const float* bn_mean    = (const float*)d_in[4];
    const float* bn_var     = (const float*)d_in[5];
    const float* var_params = (const float*)d_in[6];
    const float* lin_w      = (const float*)d_in[7];
    const float* lin_b      = (const float*)d_in[8];
    float* out = (float*)d_out;

    const int B = in_sizes[0] / 784;
    const int blocks = (B + NSAMP - 1) / NSAMP;
    quanv_fused<<<blocks, 256, 0, stream>>>(x, conv_w, bn_gamma, bn_beta, bn_mean,
                                            bn_var, var_params, lin_w, lin_b, out, B);
}

// Round 5
// 108.157 us; speedup vs baseline: 1.0490x; 1.0490x over previous
//
#include <hip/hip_runtime.h>
#include <math.h>

// QuanvolutionPlus round 9: packed-f32 (v_pk_fma_f32) patch-pair feature phase.
//
// Rounds 4/6/8 (global gathers / MFMA matvec / LDS img staging) all land at
// 110.8-113.5 total -> feature phase is VALU-issue/latency bound, not
// memory-path bound. Remaining lever: instruction count of the conv+quantum
// core (~70% of feature ops) + occupancy.
//
// Round 9:
//  - patch-PAIR processing: every float in the (verified) conv+quantum scalar
//    chains becomes float2 ext-vector -> LLVM selects VOP3P v_pk_fma_f32 /
//    v_pk_mul_f32 on gfx950 (packed dual f32): ~2x fewer VALU instrs for both
//    patches of the pair. 4 uniform hyper-iters (pairs (p, p+32), h=3 mostly
//    clamped-dup, stores masked p<196).
//  - round-6 global float2 patch gathers (round 8 proved LDS staging ==
//    global path; global needs no img buffer, no alias barriers).
//  - features flush to LDS immediately per hyper-iter (no clsr/qr register
//    accumulators: -32 VGPR in hot loop).
//  - bfrag (lin_w->f16) loads moved AFTER the feature loop (-28 live VGPR in
//    hot loop; one-time barrier drain cost ~500cyc accepted).
//  - peak ~70-75 VGPR -> __launch_bounds__(256,6): 6 blocks/CU by LDS
//    (25856B) AND VGPR -> 24 waves/CU (vs 16 in round 8).
//  - barriers 5 -> 3.
//  - MFMA matvec (16x16x32 f16, K=800, 7/7/7/4), LDS partial sum, 16-lane
//    shfl softmax: verbatim from rounds 6/8 (pass-verified).
//
// Index facts (verified rounds 1-8): cls flat n = c*196+p ; q flat n = 4p+k ;
// logits[o] = sum_n fused[n]*lin_w[o*784+n] + lin_b[o]. MFMA 16x16x32 f16:
// A row=lane&15, k=(lane>>4)*8+j ; B col=lane&15, same k ; D col=lane&15,
// row=(lane>>4)*4+reg.

typedef __fp16 h2 __attribute__((ext_vector_type(2)));
typedef __fp16 h4 __attribute__((ext_vector_type(4)));
typedef __fp16 h8 __attribute__((ext_vector_type(8)));
typedef float  f2 __attribute__((ext_vector_type(2)));
typedef float  f32x4 __attribute__((ext_vector_type(4)));

#define NSAMP 8
#define FSTRIDE 808   // f16 elems/row: 784 data + 16 zeroed pad (k=784..799) + 8 slack

__device__ __forceinline__ float rfl(float v) {
    return __int_as_float(__builtin_amdgcn_readfirstlane(__float_as_int(v)));
}

__device__ __forceinline__ f2 max0(f2 v) {
    f2 r; r.x = fmaxf(v.x, 0.f); r.y = fmaxf(v.y, 0.f); return r;
}

// round-6 verified patch gather (global float2, clamp+mask halo), pre-masked
__device__ __forceinline__ void load_patch(const float* __restrict__ xs, int p,
                                           float a[9]) {
    unsigned ii = (unsigned)p / 14u;
    int j  = p - (int)ii * 14;
    int rm = (int)ii * 56 + 2 * j;            // float index of x[2i][2j]
    float2 Rm = *(const float2*)(xs + rm);    // a11 a12
    float2 Rb = *(const float2*)(xs + rm + 28); // a21 a22
    int rt = rm - 28;  rt  = (rt  > 0) ? rt  : 0;
    float2 Rt = *(const float2*)(xs + rt);    // a01 a02
    int olt = rm - 30; olt = (olt > 0) ? olt : 0;
    float2 Lt = *(const float2*)(xs + olt);   // .y = a00
    int olm = rm - 2;  olm = (olm > 0) ? olm : 0;
    float2 Lm = *(const float2*)(xs + olm);   // .y = a10
    float2 Lb = *(const float2*)(xs + olm + 28); // .y = a20
    float mt = (ii > 0u) ? 1.f : 0.f;
    float ml = (j  > 0 ) ? 1.f : 0.f;
    a[0] = Lt.y * (mt * ml); a[1] = Rt.x * mt; a[2] = Rt.y * mt;
    a[3] = Lm.y * ml;        a[4] = Rm.x;      a[5] = Rm.y;
    a[6] = Lb.y * ml;        a[7] = Rb.x;      a[8] = Rb.y;
}

__global__ __launch_bounds__(256, 6)
void quanv_fused(const float* __restrict__ x,
                 const float* __restrict__ conv_w,
                 const float* __restrict__ bn_gamma,
                 const float* __restrict__ bn_beta,
                 const float* __restrict__ bn_mean,
                 const float* __restrict__ bn_var,
                 const float* __restrict__ var_params,
                 const float* __restrict__ lin_w,
                 const float* __restrict__ lin_b,
                 float* __restrict__ out, int B)
{
    __shared__ __align__(16) __fp16 clsB[NSAMP * FSTRIDE]; // pw aliases this later
    __shared__ __align__(16) __fp16 qB[NSAMP * FSTRIDE];

    const int tid  = threadIdx.x;
    const int lane = tid & 63;
    const int wave = tid >> 6;

    // pad k=784..799 of both buffers (A operand must be clean where B is zero)
    if (tid < 128) {
        int r = tid >> 4, buf = (tid >> 3) & 1, w = tid & 7;
        int* wp = (int*)((buf ? qB : clsB) + r * FSTRIDE + 784);
        wp[w] = 0;
    }

    // ---- uniform small params (SGPR via readfirstlane) ----
    float inv[4], addc[4];
    #pragma unroll
    for (int c = 0; c < 4; ++c) {
        float iv = bn_gamma[c] * rsqrtf(bn_var[c] + 1e-5f);
        inv[c]  = rfl(iv);
        addc[c] = rfl(bn_beta[c] - bn_mean[c] * iv);
    }
    float cv[4], sv[4];
    #pragma unroll
    for (int k = 0; k < 4; ++k) {
        float s, c;
        __sincosf(var_params[k] * 0.5f, &s, &c);
        sv[k] = rfl(s); cv[k] = rfl(c);
    }

    // ---- feature phase: 32 lanes/sample, 4 packed hyper-iters (pairs) ----
    const int s_loc = tid >> 5;    // sample in block (0..7)
    const int q32   = tid & 31;    // patch lane
    const int sg    = blockIdx.x * NSAMP + s_loc;
    const int sgc   = (sg < B) ? sg : (B - 1);
    const float* xs = x + (size_t)sgc * 784;
    __fp16* clsRow  = clsB + s_loc * FSTRIDE;
    __fp16* qRow    = qB   + s_loc * FSTRIDE;

    #pragma unroll
    for (int h = 0; h < 4; ++h) {
        const int pa = q32 + 64 * h, pb = pa + 32;
        const int pac = (pa < 196) ? pa : 195;
        const int pbc = (pb < 196) ? pb : 195;

        float A[9], Bv[9];
        load_patch(xs, pac, A);
        load_patch(xs, pbc, Bv);
        f2 aP[9];
        #pragma unroll
        for (int k2 = 0; k2 < 9; ++k2) { f2 t = {A[k2], Bv[k2]}; aP[k2] = t; }

        // conv + BN + ReLU, packed over the pair (weights splat from SGPR)
        f2 hc[4];
        #pragma unroll
        for (int c = 0; c < 4; ++c) {
            f2 hx = aP[0] * conv_w[c*9+0];
            hx += aP[1] * conv_w[c*9+1];
            hx += aP[2] * conv_w[c*9+2];
            hx += aP[3] * conv_w[c*9+3];
            hx += aP[4] * conv_w[c*9+4];
            hx += aP[5] * conv_w[c*9+5];
            hx += aP[6] * conv_w[c*9+6];
            hx += aP[7] * conv_w[c*9+7];
            hx += aP[8] * conv_w[c*9+8];
            hc[c] = max0(hx * inv[c] + addc[c]);
        }
        if (pa < 196) {
            h2 ca = __builtin_amdgcn_cvt_pkrtz(hc[0].x, hc[1].x);
            h2 cb = __builtin_amdgcn_cvt_pkrtz(hc[2].x, hc[3].x);
            __fp16* cr = clsRow + pac;
            cr[0] = ca.x; cr[196] = ca.y; cr[392] = cb.x; cr[588] = cb.y;
        }
        if (pb < 196) {
            h2 ca = __builtin_amdgcn_cvt_pkrtz(hc[0].y, hc[1].y);
            h2 cb = __builtin_amdgcn_cvt_pkrtz(hc[2].y, hc[3].y);
            __fp16* cr = clsRow + pbc;
            cr[0] = ca.x; cr[196] = ca.y; cr[392] = cb.x; cr[588] = cb.y;
        }

        // quantum chain, packed over the pair (verbatim scalar chain on f2)
        f2 haP = 0.5f * (aP[4] + aP[7]);   // a11 + a21
        f2 hbP = 0.5f * (aP[5] + aP[8]);   // a12 + a22
        float s0x, c0x, s0y, c0y, s1x, c1x, s1y, c1y;
        __sincosf(haP.x, &s0x, &c0x); __sincosf(haP.y, &s0y, &c0y);
        __sincosf(hbP.x, &s1x, &c1x); __sincosf(hbP.y, &s1y, &c1y);
        f2 c0 = {c0x, c0y}, s0 = {s0x, s0y};
        f2 c1 = {c1x, c1y}, s1 = {s1x, s1y};
        f2 m00 = c0*c1, m01 = c0*s1;
        f2 m10 = s0*s1, m11 = s0*c1;                                 // enc + CNOT(0->1)
        f2 t00 = cv[0]*m00 - sv[0]*m10, t01 = cv[0]*m01 - sv[0]*m11;
        f2 t10 = sv[0]*m00 + cv[0]*m10, t11 = sv[0]*m01 + cv[0]*m11; // RY(v0) w0
        f2 u00 = cv[1]*t00 - sv[1]*t01, u01 = sv[1]*t00 + cv[1]*t01;
        f2 u10 = cv[1]*t10 - sv[1]*t11, u11 = sv[1]*t10 + cv[1]*t11; // RY(v1) w1
        f2 w01 = u11, w11 = u01;                                      // CNOT(1->0)
        f2 p00 = cv[2]*u00 - sv[2]*u10, p01 = cv[2]*w01 - sv[2]*w11;
        f2 p10 = sv[2]*u00 + cv[2]*u10, p11 = sv[2]*w01 + cv[2]*w11; // RY(v2) w0
        f2 q00 = cv[3]*p00 - sv[3]*p01, q01 = sv[3]*p00 + cv[3]*p01;
        f2 q10 = cv[3]*p10 - sv[3]*p11, q11 = sv[3]*p10 + cv[3]*p11; // RY(v3) w1

        f2 z0 = q00*q00 + q01*q01 - q10*q10 - q11*q11;
        f2 z1 = q00*q00 + q10*q10 - q01*q01 - q11*q11;
        f2 x0 = 2.f * (q00*q10 + q01*q11);
        f2 x1 = 2.f * (q00*q01 + q10*q11);
        if (pa < 196) {
            h2 zz = __builtin_amdgcn_cvt_pkrtz(z0.x, z1.x);
            h2 xx = __builtin_amdgcn_cvt_pkrtz(x0.x, x1.x);
            h4 qv = {zz.x, zz.y, xx.x, xx.y};
            *(h4*)(qRow + 4 * pac) = qv;
        }
        if (pb < 196) {
            h2 zz = __builtin_amdgcn_cvt_pkrtz(z0.y, z1.y);
            h2 xx = __builtin_amdgcn_cvt_pkrtz(x0.y, x1.y);
            h4 qv = {zz.x, zz.y, xx.x, xx.y};
            *(h4*)(qRow + 4 * pbc) = qv;
        }
    }

    // ---- B fragments (lin_w -> f16) to registers, AFTER the hot loop ----
    const int bcol = lane & 15, bkg = lane >> 4;
    const __fp16 hz = (__fp16)0.f;
    const h8 hz8 = {hz, hz, hz, hz, hz, hz, hz, hz};
    h8 bfrag[7];
    #pragma unroll
    for (int t = 0; t < 7; ++t) {
        int st = wave * 7 + t;
        int kb = st * 32 + bkg * 8;
        h8 bf = hz8;
        if (bcol < 10 && kb < 784) {
            const float4* lw4 = (const float4*)(lin_w + bcol * 784 + kb);
            float4 v0 = lw4[0], v1 = lw4[1];
            h2 p0 = __builtin_amdgcn_cvt_pkrtz(v0.x, v0.y);
            h2 p1 = __builtin_amdgcn_cvt_pkrtz(v0.z, v0.w);
            h2 p2 = __builtin_amdgcn_cvt_pkrtz(v1.x, v1.y);
            h2 p3 = __builtin_amdgcn_cvt_pkrtz(v1.z, v1.w);
            h8 tv = {p0.x, p0.y, p1.x, p1.y, p2.x, p2.y, p3.x, p3.y};
            bf = tv;
        }
        bfrag[t] = bf;
    }

    __syncthreads();   // (1) features + pad zeros visible to all waves

    // ---- MFMA matvec: wave w owns K-steps 7w..7w+6 (st<25 valid) ----
    f32x4 acc = {0.f, 0.f, 0.f, 0.f};
    {
        const int arow = lane & 15, akg = lane >> 4;
        #pragma unroll
        for (int t = 0; t < 7; ++t) {
            int st = wave * 7 + t;
            if (st < 25) {   // wave-uniform branch
                h8 a = hz8;
                if (arow < NSAMP) {   // rows 8-15 feed zeros (MFMA half-waste: free)
                    int off = arow * FSTRIDE + st * 32 + akg * 8;
                    a = *(const h8*)(clsB + off) + *(const h8*)(qB + off); // fused add
                }
                acc = __builtin_amdgcn_mfma_f32_16x16x32_f16(a, bfrag[t], acc, 0, 0, 0);
            }
        }
    }

    __syncthreads();   // (2) all cls reads done -> safe to alias partials onto clsB
    float* pw = (float*)clsB;   // [4 waves][8 samples][16 classes]
    if (lane < 32) {            // D rows 0..7 live in lanes 0..31
        const int col = lane & 15, rb = (lane >> 4) * 4;
        #pragma unroll
        for (int r = 0; r < 4; ++r)
            pw[(wave * 8 + rb + r) * 16 + col] = acc[r];
    }
    __syncthreads();   // (3) partials visible

    // ---- cross-wave sum + per-sample softmax (16 lanes per sample) ----
    if (tid < 128) {
        const int c  = tid & 15;   // class
        const int sl = tid >> 4;   // sample in block (0..7)
        float L = pw[sl * 16 + c] + pw[(8 + sl) * 16 + c]
                + pw[(16 + sl) * 16 + c] + pw[(24 + sl) * 16 + c];
        L = (c < 10) ? (L + lin_b[c]) : -1e30f;
        float mx = L;
        mx = fmaxf(mx, __shfl_xor(mx, 1, 16));
        mx = fmaxf(mx, __shfl_xor(mx, 2, 16));
        mx = fmaxf(mx, __shfl_xor(mx, 4, 16));
        mx = fmaxf(mx, __shfl_xor(mx, 8, 16));
        float se = (c < 10) ? __expf(L - mx) : 0.f;
        se += __shfl_xor(se, 1, 16);
        se += __shfl_xor(se, 2, 16);
        se += __shfl_xor(se, 4, 16);
        se += __shfl_xor(se, 8, 16);
        const int sg2 = blockIdx.x * NSAMP + sl;
        if (c < 10 && sg2 < B)
            out[(size_t)sg2 * 10 + c] = L - mx - __logf(se);
    }
}

extern "C" void kernel_launch(void* const* d_in, const int* in_sizes, int n_in,
                              void* d_out, int out_size, void* d_ws, size_t ws_size,
                              hipStream_t stream) {
    const float* x          = (const float*)d_in[0];
    const float* conv_w     = (const float*)d_in[1];
    const float* bn_gamma   = (const float*)d_in[2];
    const float* bn_beta    = (const float*)d_in[3];
    const float* bn_mean    = (const float*)d_in[4];
    const float* bn_var     = (const float*)d_in[5];
    const float* var_params = (const float*)d_in[6];
    const float* lin_w      = (const float*)d_in[7];
    const float* lin_b      = (const float*)d_in[8];
    float* out = (float*)d_out;

    const int B = in_sizes[0] / 784;
    const int blocks = (B + NSAMP - 1) / NSAMP;
    quanv_fused<<<blocks, 256, 0, stream>>>(x, conv_w, bn_gamma, bn_beta, bn_mean,
                                            bn_var, var_params, lin_w, lin_b, out, B);
}